// Round 1
// baseline (4481.967 us; speedup 1.0000x reference)
//
#include <hip/hip_runtime.h>
#include <hip/hip_bf16.h>

typedef unsigned short u16;
typedef unsigned int u32;
typedef short  s16x8 __attribute__((ext_vector_type(8)));
typedef float  f32x4 __attribute__((ext_vector_type(4)));

#define T_STEPS 512
#define BATCH   32
#define HID     512
#define EMBD    300
#define KPAD    320
#define NGATE   2048

// ---- workspace layout (bytes) ----
#define XZ_OFF   0ull
#define XZ_BYTES (512ull*32*2048*4)          // 134,217,728  f32 [t][b][4H]
#define UB_OFF   (XZ_OFF + XZ_BYTES)
#define UB_BYTES (2048ull*512*2)             // 2,097,152  bf16 per-WG LDS images
#define WT_OFF   (UB_OFF + UB_BYTES)
#define WT_BYTES (2048ull*320*2)             // 1,310,720  bf16 [n][kpad] swizzled
#define HB_OFF   (WT_OFF + WT_BYTES)
#define HB_BYTES (2ull*32*512*2)             // 65,536  double-buffered h bf16 [b][512]
#define FL_OFF   (HB_OFF + HB_BYTES)
#define FL_BYTES 128ull                      // 32 flags

__device__ inline u16 f2b(float f) {
  u32 u = __builtin_bit_cast(u32, f);
  return (u16)((u + 0x7fffu + ((u >> 16) & 1u)) >> 16);
}

// ---------- pack W: [300][2048] f32 -> wt[n][k] bf16, k padded to 320, swizzled ----------
__global__ __launch_bounds__(64) void pack_w(const float* __restrict__ W, u16* __restrict__ wt) {
  int n = blockIdx.x;               // 0..2047
  for (int i = 0; i < 5; ++i) {
    int k = i * 64 + threadIdx.x;   // 0..319
    float v = (k < EMBD) ? W[(size_t)k * NGATE + n] : 0.f;
    u32 off = ((u32)(2 * k)) ^ (((u32)(n & 7)) << 4);
    *(u16*)((char*)wt + (size_t)n * 640 + off) = f2b(v);
  }
}

// ---------- pack U: [512][2048] f32 -> per-WG col-major swizzled bf16 LDS image ----------
// WG w owns local cols nl=0..63 : gate g = nl&3, h-col j = w*16 + (nl>>2); global col = g*512 + j
__global__ __launch_bounds__(64) void pack_u(const float* __restrict__ U, u16* __restrict__ ub) {
  int blk = blockIdx.x;             // 0..2047  = w*64 + nl
  int w = blk >> 6, nl = blk & 63;
  int gcol = (nl & 3) * 512 + w * 16 + (nl >> 2);
  for (int i = 0; i < 8; ++i) {
    int k = i * 64 + threadIdx.x;   // 0..511
    float v = U[(size_t)k * NGATE + gcol];
    u32 off = ((u32)(2 * k)) ^ (((u32)(nl & 7)) << 4);
    *(u16*)((char*)ub + (size_t)blk * 1024 + off) = f2b(v);
  }
}

// ---------- phase 1: xz[t][b][n] = emb[tok] @ W + bias (bf16 MFMA, f32 out) ----------
// tile 64(M) x 64(N), K=320 fully staged. LDS: A chunked [40][64][16B] stride 1040, B at 41600.
__global__ __launch_bounds__(256) void xz_gemm(const int* __restrict__ tokens,
                                               const float* __restrict__ emb,
                                               const u16* __restrict__ wt,
                                               const float* __restrict__ bias,
                                               float* __restrict__ xz) {
  extern __shared__ char smem[];
  const int tid = threadIdx.x;
  const int lane = tid & 63, wv = tid >> 6;
  const int m0 = (blockIdx.x >> 5) * 64;
  const int n0 = (blockIdx.x & 31) * 64;

  { // stage A: 64 rows of emb gather, f32 -> bf16, chunk layout
    int row = tid >> 2, q = tid & 3;
    int tok = tokens[m0 + row];
    const float* er = emb + (size_t)tok * EMBD;
    for (int i = 0; i < 10; ++i) {
      int k = q * 80 + i * 8;
      float4 lo = {0, 0, 0, 0}, hi = {0, 0, 0, 0};
      if (k <= 296) lo = *(const float4*)(er + k);
      if (k <= 292) hi = *(const float4*)(er + k + 4);
      u16 u[8] = {f2b(lo.x), f2b(lo.y), f2b(lo.z), f2b(lo.w),
                  f2b(hi.x), f2b(hi.y), f2b(hi.z), f2b(hi.w)};
      int kc = q * 10 + i;
      *(uint4*)(smem + kc * 1040 + row * 16) = *(uint4*)u;
    }
  }
  { // stage B: linear 40KB copy of pre-swizzled wt panel
    const uint4* src = (const uint4*)((const char*)wt + (size_t)n0 * 640);
    for (int i = 0; i < 10; ++i)
      *(uint4*)(smem + 41600 + (i * 256 + tid) * 16) = src[i * 256 + tid];
  }
  __syncthreads();

  const int mq = wv >> 1, nq = wv & 1;
  const int arow = lane & 15, kq4 = lane >> 4;
  f32x4 acc[2][2] = {};
#pragma unroll
  for (int ks = 0; ks < 10; ++ks) {
    s16x8 af[2], bfr[2];
#pragma unroll
    for (int mt = 0; mt < 2; ++mt) {
      int row = mq * 32 + mt * 16 + arow;
      int kc = ks * 4 + kq4;
      af[mt] = *(const s16x8*)(smem + kc * 1040 + row * 16);
    }
#pragma unroll
    for (int nt = 0; nt < 2; ++nt) {
      int nl = nq * 32 + nt * 16 + arow;
      u32 kb = (u32)(ks * 64 + (kq4 << 4));
      bfr[nt] = *(const s16x8*)(smem + 41600 + nl * 640 + (kb ^ (((u32)(nl & 7)) << 4)));
    }
#pragma unroll
    for (int mt = 0; mt < 2; ++mt)
#pragma unroll
      for (int nt = 0; nt < 2; ++nt)
        acc[mt][nt] = __builtin_amdgcn_mfma_f32_16x16x32_bf16(af[mt], bfr[nt], acc[mt][nt], 0, 0, 0);
  }
#pragma unroll
  for (int mt = 0; mt < 2; ++mt)
#pragma unroll
    for (int nt = 0; nt < 2; ++nt) {
      int gn = n0 + nq * 32 + nt * 16 + arow;
      float bv = bias[gn];
#pragma unroll
      for (int r = 0; r < 4; ++r) {
        int gm = m0 + mq * 32 + mt * 16 + (kq4 << 2) + r;
        int tt = gm & 511, bb = gm >> 9;         // tokens flat = b*T + t
        xz[((size_t)(tt * 32 + bb)) * NGATE + gn] = acc[mt][nt][r] + bv;
      }
    }
}

// ---------- phase 2: persistent 32-WG recurrent kernel ----------
// WG owns 64 U-cols in LDS (64KB). h double-buffered bf16 in global. flag/WG barrier.
__global__ __launch_bounds__(256) void lstm_persist(const float* __restrict__ xz,
                                                    const u16* __restrict__ ub,
                                                    u16* __restrict__ hbuf,
                                                    float* __restrict__ out,
                                                    u32* __restrict__ flags) {
  extern __shared__ char smem[];
  float* zlds = (float*)(smem + 65536);      // [32][68] f32
  const int tid = threadIdx.x;
  const int lane = tid & 63, wv = tid >> 6;
  const int wg = blockIdx.x;

  { // stage pre-swizzled U slice: linear 64KB copy
    const uint4* src = (const uint4*)(ub + (size_t)wg * 32768);
    uint4* dst = (uint4*)smem;
    for (int i = 0; i < 16; ++i) dst[i * 256 + tid] = src[i * 256 + tid];
  }
  __syncthreads();

  const int b_g = tid & 31;                  // gate-stage batch
  const int jl0 = tid >> 5;                  // 0..7 (pairs: jl0, jl0+8)
  const int arow = lane & 15, kq = lane >> 4;
  const int nl = wv * 16 + (lane & 15);
  const u32 bswz = ((u32)(nl & 7)) << 4;
  float c0 = 0.f, c1 = 0.f;

  float xzv[2][4];
  { // prefetch xz for t=0
    const float* p = xz + (size_t)b_g * NGATE + wg * 16;
#pragma unroll
    for (int e = 0; e < 2; ++e) {
      int jl = jl0 + 8 * e;
#pragma unroll
      for (int g = 0; g < 4; ++g) xzv[e][g] = p[g * 512 + jl];
    }
  }

  for (int t = 0; t < T_STEPS; ++t) {
    if (t > 0) {  // z_lds = h @ U_slice
      const char* hp = (const char*)(hbuf + (t & 1) * 16384);
      f32x4 acc0 = {0, 0, 0, 0}, acc1 = {0, 0, 0, 0};
#pragma unroll
      for (int ks = 0; ks < 16; ++ks) {
        int kb = ks * 64 + (kq << 4);
        s16x8 a0 = *(const s16x8*)(hp + arow * 1024 + kb);
        s16x8 a1 = *(const s16x8*)(hp + (arow + 16) * 1024 + kb);
        s16x8 bb = *(const s16x8*)(smem + nl * 1024 + (((u32)kb) ^ bswz));
        acc0 = __builtin_amdgcn_mfma_f32_16x16x32_bf16(a0, bb, acc0, 0, 0, 0);
        acc1 = __builtin_amdgcn_mfma_f32_16x16x32_bf16(a1, bb, acc1, 0, 0, 0);
      }
      int rb = kq * 4;
#pragma unroll
      for (int r = 0; r < 4; ++r) {
        zlds[(rb + r) * 68 + nl] = acc0[r];
        zlds[(rb + r + 16) * 68 + nl] = acc1[r];
      }
    }
    __syncthreads();

    // gates: thread handles (b_g, jl0) and (b_g, jl0+8)
    float hov[2], cov[2];
#pragma unroll
    for (int e = 0; e < 2; ++e) {
      int jl = jl0 + 8 * e;
      float4 zr = {0, 0, 0, 0};
      if (t > 0) zr = *(const float4*)&zlds[b_g * 68 + jl * 4];
      float zi = zr.x + xzv[e][0];
      float zf = zr.y + xzv[e][1];
      float zg = zr.z + xzv[e][2];
      float zo = zr.w + xzv[e][3];
      float ig = 1.f / (1.f + __expf(-zi));
      float fg = 1.f / (1.f + __expf(-zf));
      float gg = 1.f - 2.f / (__expf(2.f * zg) + 1.f);
      float og = 1.f / (1.f + __expf(-zo));
      float cc = e ? c1 : c0;
      cc = fg * cc + ig * gg;
      float hh = og * (1.f - 2.f / (__expf(2.f * cc) + 1.f));
      if (e) c1 = cc; else c0 = cc;
      hov[e] = hh; cov[e] = cc;
    }
    int j0 = wg * 16;
    if (t < T_STEPS - 1) {
      u16* hn = hbuf + ((t + 1) & 1) * 16384;
#pragma unroll
      for (int e = 0; e < 2; ++e) {
        int jl = jl0 + 8 * e;
        hn[b_g * 512 + j0 + jl] = f2b(hov[e]);
      }
    } else {
#pragma unroll
      for (int e = 0; e < 2; ++e) {
        int jl = jl0 + 8 * e;
        out[b_g * 512 + j0 + jl] = hov[e];
        out[16384 + b_g * 512 + j0 + jl] = cov[e];
      }
    }
    __syncthreads();   // drains vmcnt: all h stores reached L2 before release

    if (t < T_STEPS - 1) {
      if (tid == 0)    // release: wbl2-flush + flag publish (agent scope)
        __hip_atomic_store(&flags[wg], (u32)(t + 1), __ATOMIC_RELEASE, __HIP_MEMORY_SCOPE_AGENT);
      { // prefetch next xz while waiting
        const float* p = xz + ((size_t)(t + 1) * 32 + b_g) * NGATE + wg * 16;
#pragma unroll
        for (int e = 0; e < 2; ++e) {
          int jl = jl0 + 8 * e;
#pragma unroll
          for (int g = 0; g < 4; ++g) xzv[e][g] = p[g * 512 + jl];
        }
      }
      if (wv == 0) {  // 32 lanes poll 32 flags
        u32 tgt = (u32)(t + 1);
        for (;;) {
          u32 v = (lane < 32)
                      ? __hip_atomic_load(&flags[lane], __ATOMIC_RELAXED, __HIP_MEMORY_SCOPE_AGENT)
                      : tgt;
          if (__all(v >= tgt)) break;
          __builtin_amdgcn_s_sleep(1);
        }
      }
      __syncthreads();
      __builtin_amdgcn_fence(__ATOMIC_ACQUIRE, "agent");  // invalidate L1/L2 before reading h
    }
  }
}

extern "C" void kernel_launch(void* const* d_in, const int* in_sizes, int n_in,
                              void* d_out, int out_size, void* d_ws, size_t ws_size,
                              hipStream_t stream) {
  const int*   tokens = (const int*)d_in[0];
  const float* emb    = (const float*)d_in[1];
  const float* W      = (const float*)d_in[2];
  const float* U      = (const float*)d_in[3];
  const float* bias   = (const float*)d_in[4];
  float* out = (float*)d_out;
  char*  ws  = (char*)d_ws;

  float* xz   = (float*)(ws + XZ_OFF);
  u16*   ub   = (u16*)(ws + UB_OFF);
  u16*   wt   = (u16*)(ws + WT_OFF);
  u16*   hbuf = (u16*)(ws + HB_OFF);
  u32*   flags = (u32*)(ws + FL_OFF);

  hipMemsetAsync(flags, 0, FL_BYTES, stream);
  pack_w<<<2048, 64, 0, stream>>>(W, wt);
  pack_u<<<2048, 64, 0, stream>>>(U, ub);
  xz_gemm<<<8192, 256, 82560, stream>>>(tokens, emb, wt, bias, xz);
  lstm_persist<<<32, 256, 65536 + 32 * 68 * 4, stream>>>(xz, ub, hbuf, out, flags);
}